// Round 4
// baseline (1435.080 us; speedup 1.0000x reference)
//
#include <hip/hip_runtime.h>

#define NB 32768
#define DIN 256
#define NH 4096
#define NDOUT 256

#define KB 32            // k-window (floats); 128 B per row => 8 float4 slots
#define HSPLIT 2         // grid.y h-partitions

// ---------- numpy-pairwise-exact row sum-of-squares (n=256) ----------
__global__ __launch_bounds__(256) void rowsumsq_kernel(const float* __restrict__ A,
                                                       float* __restrict__ out, int nrows) {
    int idx = blockIdx.x * 256 + threadIdx.x;
    int row = idx >> 3;
    int j   = idx & 7;
    if (row >= nrows) return;
    const float* a = A + (size_t)row * DIN;

    float v  = a[j];
    float rA = __fmul_rn(v, v);
#pragma unroll
    for (int t = 1; t < 16; ++t) { v = a[8 * t + j];       rA = __fadd_rn(rA, __fmul_rn(v, v)); }
    v = a[128 + j];
    float rB = __fmul_rn(v, v);
#pragma unroll
    for (int t = 1; t < 16; ++t) { v = a[128 + 8 * t + j]; rB = __fadd_rn(rB, __fmul_rn(v, v)); }

#pragma unroll
    for (int m = 1; m < 8; m <<= 1) {
        rA = __fadd_rn(rA, __shfl_xor(rA, m, 8));
        rB = __fadd_rn(rB, __shfl_xor(rB, m, 8));
    }
    if (j == 0) out[row] = __fadd_rn(rA, rB);
}

// ---------- Gt[h][d] = G[d][h] ----------
__global__ __launch_bounds__(256) void transpose_kernel(const float* __restrict__ G, float* __restrict__ Gt) {
    __shared__ float tile[32][33];
    int bh = blockIdx.x;
    int bd = blockIdx.y;
    int tx = threadIdx.x & 31, ty = threadIdx.x >> 5;
#pragma unroll
    for (int u = 0; u < 4; ++u) {
        int r = ty + u * 8;
        tile[r][tx] = G[(size_t)(bd * 32 + r) * NH + bh * 32 + tx];
    }
    __syncthreads();
#pragma unroll
    for (int u = 0; u < 4; ++u) {
        int r = ty + u * 8;
        Gt[(size_t)(bh * 32 + r) * NDOUT + bd * 32 + tx] = tile[tx][r];
    }
}

// ---------- argmin: block = 64 rows x 256 cols/h-iter, 8x8 per-lane frag ----------
// LDS float4-slot layout (swizzled):  slot(r, kb) = (r<<3) | (kb ^ ((r>>2)&7))
// Read instr for fragment (row group): 8 distinct addresses (one per ly/lx) land on
// 8 distinct bank-quads (quad = kb^ly), each broadcast to 8 lanes -> conflict-free.
__global__ __launch_bounds__(256) void argmin_kernel(const float* __restrict__ X, const float* __restrict__ W,
                                                     const float* __restrict__ x2, const float* __restrict__ w2,
                                                     float* __restrict__ bestV_out, int* __restrict__ bestI_out) {
    __shared__ float Xs[64 * KB];    // 8 KB
    __shared__ float Ws[256 * KB];   // 32 KB
    __shared__ float w2s[256];
    __shared__ float x2s[64];
    __shared__ float redV[4][64];
    __shared__ int   redI[4][64];

    float4* X4s = reinterpret_cast<float4*>(Xs);
    float4* W4s = reinterpret_cast<float4*>(Ws);

    const int tid  = threadIdx.x;
    const int wave = tid >> 6;
    const int lane = tid & 63;
    const int lx = lane & 7, ly = lane >> 3;
    const int b0 = blockIdx.x * 64;
    const int hbase = blockIdx.y * (NH / HSPLIT);

    float bV[8];
    int   bI[8];
#pragma unroll
    for (int ri = 0; ri < 8; ++ri) { bV[ri] = 1e30f; bI[ri] = 0; }

    if (tid < 64) x2s[tid] = x2[b0 + tid];

    const float4* X4 = reinterpret_cast<const float4*>(X);
    const float4* W4 = reinterpret_cast<const float4*>(W);

    for (int hi = 0; hi < (NH / HSPLIT) / 256; ++hi) {
        const int h0 = hbase + hi * 256;

        __syncthreads();   // prev epilogue done before w2s/Ws overwritten
        if (tid < 64) reinterpret_cast<float4*>(w2s)[tid] = reinterpret_cast<const float4*>(w2 + h0)[tid];

        float acc[8][8];
#pragma unroll
        for (int ri = 0; ri < 8; ++ri)
#pragma unroll
            for (int ci = 0; ci < 8; ++ci) acc[ri][ci] = 0.f;

        for (int kc = 0; kc < DIN; kc += KB) {
            if (kc) __syncthreads();   // prev window compute done before restage
            // stage X: 512 float4, 2 per thread
#pragma unroll
            for (int u = 0; u < 2; ++u) {
                int idx = tid + 256 * u;
                int r = idx >> 3, kb = idx & 7;
                float4 v = X4[(size_t)(b0 + r) * (DIN / 4) + (kc >> 2) + kb];
                X4s[(r << 3) | (kb ^ ((r >> 2) & 7))] = v;
            }
            // stage W: 2048 float4, 8 per thread
#pragma unroll
            for (int u = 0; u < 8; ++u) {
                int idx = tid + 256 * u;
                int c = idx >> 3, kb = idx & 7;
                float4 v = W4[(size_t)(h0 + c) * (DIN / 4) + (kc >> 2) + kb];
                W4s[(c << 3) | (kb ^ ((c >> 2) & 7))] = v;
            }
            __syncthreads();
            // compute: 8 kb-steps, k ascending (kb asc, then .x.y.z.w) == reference chain
#pragma unroll
            for (int kb = 0; kb < 8; ++kb) {
                const int xk = kb ^ ly;
                const int wk = kb ^ lx;
                float4 xv[8];
#pragma unroll
                for (int ri = 0; ri < 8; ++ri) {
                    int r = 4 * ly + 32 * (ri >> 2) + (ri & 3);
                    xv[ri] = X4s[(r << 3) | xk];
                }
#pragma unroll
                for (int ci = 0; ci < 8; ++ci) {
                    int ct = wave * 64 + 4 * lx + 32 * (ci >> 2) + (ci & 3);
                    float4 wv = W4s[(ct << 3) | wk];
#pragma unroll
                    for (int ri = 0; ri < 8; ++ri) {
                        acc[ri][ci] = fmaf(xv[ri].x, wv.x, acc[ri][ci]);
                        acc[ri][ci] = fmaf(xv[ri].y, wv.y, acc[ri][ci]);
                        acc[ri][ci] = fmaf(xv[ri].z, wv.z, acc[ri][ci]);
                        acc[ri][ci] = fmaf(xv[ri].w, wv.w, acc[ri][ci]);
                    }
                }
            }
        }
        // epilogue: d = fl(fl(x2 - 2m) + w2), running argmin, cols ascending per lane
        float x2r[8];
#pragma unroll
        for (int ri = 0; ri < 8; ++ri) x2r[ri] = x2s[4 * ly + 32 * (ri >> 2) + (ri & 3)];
#pragma unroll
        for (int ci = 0; ci < 8; ++ci) {
            int ct = wave * 64 + 4 * lx + 32 * (ci >> 2) + (ci & 3);
            int c  = h0 + ct;
            float wc = w2s[ct];
#pragma unroll
            for (int ri = 0; ri < 8; ++ri) {
                float t = fmaf(-2.f, acc[ri][ci], x2r[ri]);
                float d = __fadd_rn(t, wc);
                if (d < bV[ri]) { bV[ri] = d; bI[ri] = c; }
            }
        }
    }

    // merge across lx (8 lanes share each row), tie -> lowest index
#pragma unroll
    for (int ri = 0; ri < 8; ++ri) {
        float v = bV[ri]; int idx = bI[ri];
#pragma unroll
        for (int m = 1; m < 8; m <<= 1) {
            float ov = __shfl_xor(v, m, 64);
            int   oi = __shfl_xor(idx, m, 64);
            if (ov < v || (ov == v && oi < idx)) { v = ov; idx = oi; }
        }
        if (lx == 0) {
            int r = 4 * ly + 32 * (ri >> 2) + (ri & 3);
            redV[wave][r] = v; redI[wave][r] = idx;
        }
    }
    __syncthreads();
    if (tid < 64) {
        float v = redV[0][tid]; int idx = redI[0][tid];
#pragma unroll
        for (int wv_ = 1; wv_ < 4; ++wv_) {
            float ov = redV[wv_][tid]; int oi = redI[wv_][tid];
            if (ov < v || (ov == v && oi < idx)) { v = ov; idx = oi; }
        }
        bestV_out[blockIdx.y * NB + b0 + tid] = v;
        bestI_out[blockIdx.y * NB + b0 + tid] = idx;
    }
}

// ---------- merge h-splits, gather output rows + winner indices ----------
__global__ __launch_bounds__(256) void gather_kernel(const float* __restrict__ Gt,
                                                     const float* __restrict__ bestV, const int* __restrict__ bestI,
                                                     float* __restrict__ out) {
    int b = blockIdx.x;
    float v0 = bestV[b];         int i0 = bestI[b];
    float v1 = bestV[NB + b];    int i1 = bestI[NB + b];
    int w = (v1 < v0 || (v1 == v0 && i1 < i0)) ? i1 : i0;
    out[(size_t)b * NDOUT + threadIdx.x] = Gt[(size_t)w * NDOUT + threadIdx.x];
    if (threadIdx.x == 0) out[(size_t)NB * NDOUT + b] = (float)w;
}

extern "C" void kernel_launch(void* const* d_in, const int* in_sizes, int n_in,
                              void* d_out, int out_size, void* d_ws, size_t ws_size,
                              hipStream_t stream) {
    const float* x  = (const float*)d_in[0];
    const float* Wk = (const float*)d_in[1];
    const float* Gw = (const float*)d_in[2];
    float* out = (float*)d_out;

    char* ws = (char*)d_ws;
    float* w2    = (float*)ws;                          // 16 KB
    float* x2    = (float*)(ws + 16384);                // 128 KB
    float* bestV = (float*)(ws + 16384 + 131072);       // 2*128 KB
    int*   bestI = (int*)(ws + 16384 + 131072 + 262144);// 2*128 KB
    float* Gt    = (float*)(ws + 16384 + 131072 + 262144 + 262144);  // 4 MB

    hipLaunchKernelGGL(rowsumsq_kernel,  dim3((NH * 8) / 256),        dim3(256), 0, stream, Wk, w2, NH);
    hipLaunchKernelGGL(rowsumsq_kernel,  dim3((NB * 8) / 256),        dim3(256), 0, stream, x, x2, NB);
    hipLaunchKernelGGL(transpose_kernel, dim3(NH / 32, NDOUT / 32),   dim3(256), 0, stream, Gw, Gt);
    hipLaunchKernelGGL(argmin_kernel,    dim3(NB / 64, HSPLIT),       dim3(256), 0, stream, x, Wk, x2, w2, bestV, bestI);
    hipLaunchKernelGGL(gather_kernel,    dim3(NB),                    dim3(256), 0, stream, Gt, bestV, bestI, out);
}

// Round 5
// 630.543 us; speedup vs baseline: 2.2759x; 2.2759x over previous
//
#include <hip/hip_runtime.h>

#define NB 32768
#define DIN 256
#define NH 4096
#define NDOUT 256
#define DELTA 0.06f

typedef _Float16 f16x8 __attribute__((ext_vector_type(8)));
typedef _Float16 f16x4 __attribute__((ext_vector_type(4)));
typedef float f32x4 __attribute__((ext_vector_type(4)));

// ---------- numpy-pairwise-exact row sum-of-squares (n=256) ---------- (verified bit-exact r3)
__global__ __launch_bounds__(256) void rowsumsq_kernel(const float* __restrict__ A,
                                                       float* __restrict__ out, int nrows) {
    int idx = blockIdx.x * 256 + threadIdx.x;
    int row = idx >> 3;
    int j   = idx & 7;
    if (row >= nrows) return;
    const float* a = A + (size_t)row * DIN;

    float v  = a[j];
    float rA = __fmul_rn(v, v);
#pragma unroll
    for (int t = 1; t < 16; ++t) { v = a[8 * t + j];       rA = __fadd_rn(rA, __fmul_rn(v, v)); }
    v = a[128 + j];
    float rB = __fmul_rn(v, v);
#pragma unroll
    for (int t = 1; t < 16; ++t) { v = a[128 + 8 * t + j]; rB = __fadd_rn(rB, __fmul_rn(v, v)); }

#pragma unroll
    for (int m = 1; m < 8; m <<= 1) {
        rA = __fadd_rn(rA, __shfl_xor(rA, m, 8));
        rB = __fadd_rn(rB, __shfl_xor(rB, m, 8));
    }
    if (j == 0) out[row] = __fadd_rn(rA, rB);
}

// ---------- Gt[h][d] = G[d][h] ----------
__global__ __launch_bounds__(256) void transpose_kernel(const float* __restrict__ G, float* __restrict__ Gt) {
    __shared__ float tile[32][33];
    int bh = blockIdx.x;
    int bd = blockIdx.y;
    int tx = threadIdx.x & 31, ty = threadIdx.x >> 5;
#pragma unroll
    for (int u = 0; u < 4; ++u) {
        int r = ty + u * 8;
        tile[r][tx] = G[(size_t)(bd * 32 + r) * NH + bh * 32 + tx];
    }
    __syncthreads();
#pragma unroll
    for (int u = 0; u < 4; ++u) {
        int r = ty + u * 8;
        Gt[(size_t)(bh * 32 + r) * NDOUT + bd * 32 + tx] = tile[tx][r];
    }
}

// ---------- fp32 -> fp16 convert (RN), 4 elems/thread ----------
__global__ __launch_bounds__(256) void tohalf_kernel(const float* __restrict__ in, _Float16* __restrict__ out, int n4) {
    int i = blockIdx.x * 256 + threadIdx.x;
    if (i >= n4) return;
    float4 v = reinterpret_cast<const float4*>(in)[i];
    f16x4 h;
    h[0] = (_Float16)v.x; h[1] = (_Float16)v.y; h[2] = (_Float16)v.z; h[3] = (_Float16)v.w;
    reinterpret_cast<f16x4*>(out)[i] = h;
}

// ---------- approx GEMM-argmin: fp16 MFMA, per-(row,16-col-tile) minima ----------
// 128x128 tile, 4 waves (2x2), wave = 64x64 via 4x4 frags of 16x16x32_f16.
// LDS row pitch = 5 float4-units (80 B): quad-index step 5 mod 8 -> all 8 bank-quads, 2-way (free).
__global__ __launch_bounds__(256) void approx_kernel(const _Float16* __restrict__ Xh, const _Float16* __restrict__ Wh,
                                                     const float* __restrict__ w2, float* __restrict__ tileMin) {
    __shared__ float4 A4[128 * 5];
    __shared__ float4 B4[128 * 5];
    const int tid  = threadIdx.x;
    const int lane = tid & 63;
    const int wid  = tid >> 6;
    const int wr = wid >> 1, wc = wid & 1;
    const int r0 = blockIdx.x * 128;
    const int c0 = blockIdx.y * 128;

    const float4* Xg = reinterpret_cast<const float4*>(Xh);  // row = 32 float4-units (256 halfs)
    const float4* Wg = reinterpret_cast<const float4*>(Wh);

    f32x4 acc[4][4];
#pragma unroll
    for (int i = 0; i < 4; ++i)
#pragma unroll
        for (int j = 0; j < 4; ++j) acc[i][j] = {0.f, 0.f, 0.f, 0.f};

    for (int kc8 = 0; kc8 < 32; kc8 += 4) {   // k window: 4 units = 32 halfs
        __syncthreads();
#pragma unroll
        for (int it = 0; it < 2; ++it) {
            int u = tid + 256 * it;            // 512 units: 128 rows x 4 kg
            int r = u >> 2, kg = u & 3;
            A4[r * 5 + kg] = Xg[(size_t)(r0 + r) * 32 + kc8 + kg];
            B4[r * 5 + kg] = Wg[(size_t)(c0 + r) * 32 + kc8 + kg];
        }
        __syncthreads();
        f16x8 af[4], bf[4];
#pragma unroll
        for (int fi = 0; fi < 4; ++fi)
            af[fi] = *reinterpret_cast<const f16x8*>(&A4[(wr * 64 + 16 * fi + (lane & 15)) * 5 + (lane >> 4)]);
#pragma unroll
        for (int fj = 0; fj < 4; ++fj)
            bf[fj] = *reinterpret_cast<const f16x8*>(&B4[(wc * 64 + 16 * fj + (lane & 15)) * 5 + (lane >> 4)]);
#pragma unroll
        for (int fi = 0; fi < 4; ++fi)
#pragma unroll
            for (int fj = 0; fj < 4; ++fj)
                acc[fi][fj] = __builtin_amdgcn_mfma_f32_16x16x32_f16(af[fi], bf[fj], acc[fi][fj], 0, 0, 0);
    }

    // epilogue: d~ = w2[c] - 2*m~ ; min over 16 cols per 16-col tile; scattered store
#pragma unroll
    for (int fj = 0; fj < 4; ++fj) {
        int cb = c0 + wc * 64 + 16 * fj;
        float w2c = w2[cb + (lane & 15)];
        int ctile = cb >> 4;
#pragma unroll
        for (int fi = 0; fi < 4; ++fi) {
#pragma unroll
            for (int reg = 0; reg < 4; ++reg) {
                float d = fmaf(-2.f, acc[fi][fj][reg], w2c);
#pragma unroll
                for (int m = 1; m < 16; m <<= 1) d = fminf(d, __shfl_xor(d, m, 16));
                if ((lane & 15) == 0) {
                    int row = r0 + wr * 64 + 16 * fi + 4 * (lane >> 4) + reg;
                    tileMin[(size_t)row * 256 + ctile] = d;
                }
            }
        }
    }
}

// ---------- per-row: gmin over tile minima, exact rescore of candidate tiles, gather ----------
__global__ __launch_bounds__(256) void rescore_kernel(const float* __restrict__ X, const float* __restrict__ W,
                                                      const float* __restrict__ x2, const float* __restrict__ w2,
                                                      const float* __restrict__ tileMin, const float* __restrict__ Gt,
                                                      float* __restrict__ out) {
    __shared__ float4 Xrow[4][64];
    const int tid  = threadIdx.x;
    const int lane = tid & 63;
    const int w    = tid >> 6;
    const int r    = blockIdx.x * 4 + w;

    float4 v4 = reinterpret_cast<const float4*>(tileMin)[(size_t)r * 64 + lane];
    float m0 = fminf(fminf(v4.x, v4.y), fminf(v4.z, v4.w));
#pragma unroll
    for (int i = 1; i < 64; i <<= 1) m0 = fminf(m0, __shfl_xor(m0, i, 64));
    const float thr = m0 + DELTA;

    Xrow[w][lane] = reinterpret_cast<const float4*>(X)[(size_t)r * 64 + lane];
    const float x2r = x2[r];

    float bv = 1e30f; int bi = 0x7fffffff;
    const float4* W4 = reinterpret_cast<const float4*>(W);
    float tv[4] = {v4.x, v4.y, v4.z, v4.w};

#pragma unroll
    for (int s = 0; s < 4; ++s) {
        unsigned long long mask = __ballot(tv[s] <= thr);
        while (mask) {
            int L = __ffsll(mask) - 1;
            mask &= mask - 1;
            int ct = L * 4 + s;
            int c  = ct * 16 + (lane & 15);      // lanes 16-63 duplicate cols (broadcast loads)
            // exact reference dot: sequential fmaf, k ascending
            float m = 0.f;
#pragma unroll 8
            for (int kk = 0; kk < 64; ++kk) {
                float4 wv = W4[(size_t)c * 64 + kk];
                float4 xv = Xrow[w][kk];
                m = fmaf(xv.x, wv.x, m);
                m = fmaf(xv.y, wv.y, m);
                m = fmaf(xv.z, wv.z, m);
                m = fmaf(xv.w, wv.w, m);
            }
            float t = fmaf(-2.f, m, x2r);        // fl(x2 - 2m), 2m exact
            float d = __fadd_rn(t, w2[c]);       // fl(t + w2)
            int ci = c;
#pragma unroll
            for (int i = 1; i < 16; i <<= 1) {
                float od = __shfl_xor(d, i, 16);
                int   oc = __shfl_xor(ci, i, 16);
                if (od < d || (od == d && oc < ci)) { d = od; ci = oc; }
            }
            if (d < bv || (d == bv && ci < bi)) { bv = d; bi = ci; }
        }
    }
    reinterpret_cast<float4*>(out)[(size_t)r * 64 + lane] =
        reinterpret_cast<const float4*>(Gt)[(size_t)bi * 64 + lane];
    if (lane == 0) out[(size_t)NB * NDOUT + r] = (float)bi;
}

extern "C" void kernel_launch(void* const* d_in, const int* in_sizes, int n_in,
                              void* d_out, int out_size, void* d_ws, size_t ws_size,
                              hipStream_t stream) {
    const float* x  = (const float*)d_in[0];
    const float* Wk = (const float*)d_in[1];
    const float* Gw = (const float*)d_in[2];
    float* out = (float*)d_out;

    char* ws = (char*)d_ws;
    float*     w2      = (float*)(ws);                        // 16 KB
    float*     x2      = (float*)(ws + (1u << 20));           // 128 KB
    float*     Gt      = (float*)(ws + (2u << 20));           // 4 MB
    _Float16*  Xh      = (_Float16*)(ws + (6u << 20));        // 16 MB
    _Float16*  Wh      = (_Float16*)(ws + (22u << 20));       // 2 MB
    float*     tileMin = (float*)(ws + (24u << 20));          // 32 MB  (total 56 MB)

    hipLaunchKernelGGL(rowsumsq_kernel,  dim3((NH * 8) / 256),      dim3(256), 0, stream, Wk, w2, NH);
    hipLaunchKernelGGL(rowsumsq_kernel,  dim3((NB * 8) / 256),      dim3(256), 0, stream, x, x2, NB);
    hipLaunchKernelGGL(transpose_kernel, dim3(NH / 32, NDOUT / 32), dim3(256), 0, stream, Gw, Gt);
    hipLaunchKernelGGL(tohalf_kernel,    dim3((NB * DIN / 4) / 256), dim3(256), 0, stream, x, Xh, NB * DIN / 4);
    hipLaunchKernelGGL(tohalf_kernel,    dim3((NH * DIN / 4) / 256), dim3(256), 0, stream, Wk, Wh, NH * DIN / 4);
    hipLaunchKernelGGL(approx_kernel,    dim3(NB / 128, NH / 128),  dim3(256), 0, stream, Xh, Wh, w2, tileMin);
    hipLaunchKernelGGL(rescore_kernel,   dim3(NB / 4),              dim3(256), 0, stream, x, Wk, x2, w2, tileMin, Gt, out);
}